// Round 11
// baseline (526.781 us; speedup 1.0000x reference)
//
#include <hip/hip_runtime.h>
#include <hip/hip_bf16.h>

#define BN_EPS 1e-5f
#define BINSHIFT 6
#define BINW 64
#define NBLK 1024          // chunks for the contention-free counting sort
#define NSEG 8
#define SEGW (NBLK / NSEG) // 128

// ---- bf16 helpers (RN rounding) ----
__device__ __forceinline__ unsigned pk_bf16(float x, float y) {
    unsigned ux = __float_as_uint(x);
    ux += 0x7FFFu + ((ux >> 16) & 1u);
    unsigned uy = __float_as_uint(y);
    uy += 0x7FFFu + ((uy >> 16) & 1u);
    return (ux >> 16) | (uy & 0xFFFF0000u);
}
__device__ __forceinline__ unsigned short f2bf(float x) {
    unsigned u = __float_as_uint(x);
    u += 0x7FFFu + ((u >> 16) & 1u);
    return (unsigned short)(u >> 16);
}
__device__ __forceinline__ float bfu(unsigned short u) {
    return __uint_as_float((unsigned)u << 16);
}
__device__ __forceinline__ float bf_lo(unsigned u) { return __uint_as_float(u << 16); }
__device__ __forceinline__ float bf_hi(unsigned u) { return __uint_as_float(u & 0xFFFF0000u); }

// XCD-aware chunk swizzle.
__device__ __forceinline__ int chunk_of(int bid) {
    return ((bid & 7) << 7) | (bid >> 3);   // NBLK = 1024
}

// ===========================================================================
// x fp32 -> bf16 conversion (streaming, once).
// ===========================================================================
__global__ __launch_bounds__(256)
void cvt_x_kernel(const float* __restrict__ x, unsigned* __restrict__ xbf,
                  int nword) {   // nword = N*32/2 packed words
    int i = blockIdx.x * 256 + threadIdx.x;
    if (i >= nword) return;
    float2 v = ((const float2*)x)[i];
    xbf[i] = pk_bf16(v.x, v.y);
}

// ===========================================================================
// Preprocessing (unchanged from round 10): counting sort by bin = dst>>6,
// transposed-scan, bf16 ea carried through, per-bin fine sort.
// ===========================================================================

__global__ __launch_bounds__(256)
void hist2d_kernel(const int* __restrict__ dst, int* __restrict__ histmatT,
                   int E, int nbins, int chunk) {
    __shared__ int h[2048];
    for (int i = threadIdx.x; i < nbins; i += 256) h[i] = 0;
    __syncthreads();
    int c = chunk_of(blockIdx.x);
    int e0 = c * chunk;
    int e1 = min(E, e0 + chunk);
    for (int e = e0 + threadIdx.x; e < e1; e += 256)
        atomicAdd(&h[dst[e] >> BINSHIFT], 1);
    __syncthreads();
    for (int i = threadIdx.x; i < nbins; i += 256)
        histmatT[(size_t)i * NBLK + c] = h[i];
}

__global__ __launch_bounds__(256)
void colsum_kernel(const int* __restrict__ histmatT, int* __restrict__ bincnt,
                   int* __restrict__ segsum, int nbins) {
    int bin = blockIdx.x * 256 + threadIdx.x;
    if (bin >= nbins) return;
    const int* col = histmatT + (size_t)bin * NBLK;
    int tot = 0;
#pragma unroll
    for (int s = 0; s < NSEG; ++s) {
        int ps = 0;
#pragma unroll 16
        for (int r = 0; r < SEGW; ++r) ps += col[s * SEGW + r];
        segsum[s * nbins + bin] = ps;
        tot += ps;
    }
    bincnt[bin] = tot;
}

__global__ __launch_bounds__(1024)
void bin_scan_kernel(const int* __restrict__ bincnt, int* __restrict__ binstart,
                     int nbins, int E) {
    __shared__ int a[2048];
    __shared__ int b[1024];
    int t = threadIdx.x;
    a[t]        = (t < nbins) ? bincnt[t] : 0;
    a[t + 1024] = (t + 1024 < nbins) ? bincnt[t + 1024] : 0;
    __syncthreads();
    b[t] = a[2 * t] + a[2 * t + 1];
    __syncthreads();
    for (int off = 1; off < 1024; off <<= 1) {
        int v = (t >= off) ? b[t - off] : 0;
        __syncthreads();
        b[t] += v;
        __syncthreads();
    }
    int base = (t == 0) ? 0 : b[t - 1];
    if (2 * t < nbins)     binstart[2 * t]     = base;
    if (2 * t + 1 < nbins) binstart[2 * t + 1] = base + a[2 * t];
    if (t == 0) binstart[nbins] = E;
}

__global__ __launch_bounds__(256)
void rowscan_kernel(const int* __restrict__ histmatT, const int* __restrict__ binstart,
                    const int* __restrict__ segsum, int* __restrict__ basemat,
                    int nbins) {
    int bin = blockIdx.x * 256 + threadIdx.x;
    if (bin >= nbins) return;
    int seg = blockIdx.y;
    int base = binstart[bin];
    for (int s = 0; s < seg; ++s) base += segsum[s * nbins + bin];
    const int* col = histmatT + (size_t)bin * NBLK + seg * SEGW;
#pragma unroll 8
    for (int r = 0; r < SEGW; ++r) {
        int v = col[r];
        basemat[(size_t)(seg * SEGW + r) * nbins + bin] = base;
        base += v;
    }
}

__global__ __launch_bounds__(256)
void place_kernel(const int* __restrict__ src, const int* __restrict__ dst,
                  const float* __restrict__ edge_attr,
                  const int* __restrict__ basemat,
                  int* __restrict__ tmp_meta, uint4* __restrict__ tmp_ea,
                  int E, int nbins, int chunk) {
    __shared__ int cur[2048];
    int c = chunk_of(blockIdx.x);
    const int* row = basemat + (size_t)c * nbins;
    for (int i = threadIdx.x; i < nbins; i += 256) cur[i] = row[i];
    __syncthreads();
    int e0 = c * chunk;
    int e1 = min(E, e0 + chunk);
    for (int e = e0 + threadIdx.x; e < e1; e += 256) {
        int d = dst[e];
        int bin = d >> BINSHIFT;
        int pos = atomicAdd(&cur[bin], 1);
        tmp_meta[pos] = ((d & (BINW - 1)) << 20) | src[e];  // src < 2^20
        const float4* sp = (const float4*)(edge_attr + (size_t)e * 8);
        float4 a0 = sp[0], a1 = sp[1];
        uint4 pkd;
        pkd.x = pk_bf16(a0.x, a0.y);
        pkd.y = pk_bf16(a0.z, a0.w);
        pkd.z = pk_bf16(a1.x, a1.y);
        pkd.w = pk_bf16(a1.z, a1.w);
        tmp_ea[pos] = pkd;
    }
}

__global__ __launch_bounds__(256)
void pass2_kernel(const int* __restrict__ binstart, const int* __restrict__ tmp_meta,
                  const uint4* __restrict__ tmp_ea,
                  int* __restrict__ rowstart, int* __restrict__ src_sorted,
                  uint4* __restrict__ ea_sorted, int N, int E) {
    __shared__ int s_cur[BINW];
    int b = blockIdx.x;
    int node0 = b << BINSHIFT;
    int e0 = binstart[b], e1 = binstart[b + 1];
    int t = threadIdx.x;

    if (t < BINW) s_cur[t] = 0;
    __syncthreads();

    for (int e = e0 + t; e < e1; e += 256)
        atomicAdd(&s_cur[tmp_meta[e] >> 20], 1);
    __syncthreads();

    if (t < BINW) {
        int val = s_cur[t];
        int inc = val;
#pragma unroll
        for (int off = 1; off < 64; off <<= 1) {
            int n = __shfl_up(inc, off);
            if (t >= off) inc += n;
        }
        int excl = e0 + inc - val;
        s_cur[t] = excl;
        int node = node0 + t;
        if (node <= N) rowstart[node] = excl;
    }
    __syncthreads();

    for (int e = e0 + t; e < e1; e += 256) {
        int mx = tmp_meta[e];
        int dl   = mx >> 20;
        int srcv = mx & 0xFFFFF;
        int fpos = atomicAdd(&s_cur[dl], 1);
        src_sorted[fpos] = srcv;
        ea_sorted[fpos] = tmp_ea[e];
    }
}

// ===========================================================================
// Fused GINE layer — WAVE PER NODE, edge-parallel slots, pair-unrolled
// gathers (2 outstanding x loads/lane), bf16 x (all layers), bf16 ea.
// ===========================================================================
__device__ __forceinline__ void edge_mlp_acc(uint4 ev, const float xr[4],
                                             const float ew_r[8][4],
                                             const float eb_r[4], float acc[4]) {
    float av[8] = {bf_lo(ev.x), bf_hi(ev.x), bf_lo(ev.y), bf_hi(ev.y),
                   bf_lo(ev.z), bf_hi(ev.z), bf_lo(ev.w), bf_hi(ev.w)};
#pragma unroll
    for (int j = 0; j < 4; ++j) {
        float lin = eb_r[j];
#pragma unroll
        for (int k = 0; k < 8; ++k) lin = fmaf(av[k], ew_r[k][j], lin);
        lin += xr[j];
        acc[j] += (lin > 0.f ? lin : 0.f);
    }
}

template<int DIN, int C, int S>
__global__ __launch_bounds__(256)
void gine_layer_wave(const unsigned short* __restrict__ xb,  // [N, DIN] bf16
                     const int*   __restrict__ rowstart,   // [N+1]
                     const int*   __restrict__ src_sorted, // [E]
                     const uint4* __restrict__ ea_sorted,  // [E] bf16x8
                     const float* __restrict__ ew, const float* __restrict__ eb,
                     const float* __restrict__ wa, const float* __restrict__ ba,
                     const float* __restrict__ g, const float* __restrict__ be,
                     const float* __restrict__ m, const float* __restrict__ v,
                     const float* __restrict__ wb, const float* __restrict__ bb,
                     unsigned short* __restrict__ hout,    // [N, 16] bf16
                     int N) {
    static_assert(C * S == 64 && C * 4 == DIN, "lane layout");
    constexpr int PAD = DIN + 1;

    __shared__ float s_wa[DIN * 16];
    __shared__ float s_wb[256];
    __shared__ float s_ba[16], s_scale[16], s_shift[16], s_bb[16];
    __shared__ float s_s[16 * PAD];
    __shared__ float s_h[16 * 17];

    int t = threadIdx.x;
    for (int idx = t; idx < DIN * 16; idx += 256) s_wa[idx] = wa[idx];
    s_wb[t] = wb[t];
    if (t < 16) {
        s_ba[t] = ba[t];
        float sc = g[t] * rsqrtf(v[t] + BN_EPS);
        s_scale[t] = sc;
        s_shift[t] = be[t] - m[t] * sc;
        s_bb[t] = bb[t];
    }

    int w    = t >> 6;        // wave id (0..3)
    int lane = t & 63;
    int c    = lane / S;      // channel group
    int s    = lane % S;      // edge slot
    int c0   = c * 4;

    float ew_r[8][4];
#pragma unroll
    for (int k = 0; k < 8; ++k) {
        float4 wv = *(const float4*)(ew + k * DIN + c0);
        ew_r[k][0] = wv.x; ew_r[k][1] = wv.y; ew_r[k][2] = wv.z; ew_r[k][3] = wv.w;
    }
    float4 ebv = *(const float4*)(eb + c0);
    float eb_r[4] = {ebv.x, ebv.y, ebv.z, ebv.w};

    int node0 = blockIdx.x * 16;

#pragma unroll
    for (int q = 0; q < 4; ++q) {
        int nl = w * 4 + q;
        int i  = node0 + nl;
        float acc[4] = {0.f, 0.f, 0.f, 0.f};
        if (i < N) {
            int e0r = rowstart[i];
            int e1r = rowstart[i + 1];
            int e   = e0r + s;
            int svA = (e < e1r) ? src_sorted[e] : 0;
            int svB = (e + S < e1r) ? src_sorted[e + S] : 0;
            // pair loop: 2 outstanding x gathers + 2 ea loads per iteration
            for (; e + S < e1r; e += 2 * S) {
                int svA_n = (e + 2 * S < e1r) ? src_sorted[e + 2 * S] : 0;
                int svB_n = (e + 3 * S < e1r) ? src_sorted[e + 3 * S] : 0;
                uint4 evA = ea_sorted[e];
                uint4 evB = ea_sorted[e + S];
                ushort4 xvA = *(const ushort4*)(xb + (size_t)svA * DIN + c0);
                ushort4 xvB = *(const ushort4*)(xb + (size_t)svB * DIN + c0);
                float xrA[4] = {bfu(xvA.x), bfu(xvA.y), bfu(xvA.z), bfu(xvA.w)};
                float xrB[4] = {bfu(xvB.x), bfu(xvB.y), bfu(xvB.z), bfu(xvB.w)};
                edge_mlp_acc(evA, xrA, ew_r, eb_r, acc);
                edge_mlp_acc(evB, xrB, ew_r, eb_r, acc);
                svA = svA_n;
                svB = svB_n;
            }
            if (e < e1r) {   // tail (single)
                uint4 evA = ea_sorted[e];
                ushort4 xvA = *(const ushort4*)(xb + (size_t)svA * DIN + c0);
                float xrA[4] = {bfu(xvA.x), bfu(xvA.y), bfu(xvA.z), bfu(xvA.w)};
                edge_mlp_acc(evA, xrA, ew_r, eb_r, acc);
            }
        }
#pragma unroll
        for (int mask = S >> 1; mask >= 1; mask >>= 1) {
#pragma unroll
            for (int j = 0; j < 4; ++j) acc[j] += __shfl_xor(acc[j], mask);
        }
        if (s == 0 && i < N) {
            ushort4 xv = *(const ushort4*)(xb + (size_t)i * DIN + c0);
            s_s[nl * PAD + c0 + 0] = acc[0] + bfu(xv.x);
            s_s[nl * PAD + c0 + 1] = acc[1] + bfu(xv.y);
            s_s[nl * PAD + c0 + 2] = acc[2] + bfu(xv.z);
            s_s[nl * PAD + c0 + 3] = acc[3] + bfu(xv.w);
        }
    }
    __syncthreads();

    int nl2 = t >> 4;
    int j   = t & 15;
    float a = s_ba[j];
#pragma unroll
    for (int k = 0; k < DIN; ++k)
        a = fmaf(s_s[nl2 * PAD + k], s_wa[k * 16 + j], a);
    a = a * s_scale[j] + s_shift[j];
    s_h[nl2 * 17 + j] = a > 0.f ? a : 0.f;
    __syncthreads();

    float o = s_bb[j];
#pragma unroll
    for (int k = 0; k < 16; ++k)
        o = fmaf(s_h[nl2 * 17 + k], s_wb[k * 16 + j], o);
    o = o > 0.f ? o : 0.f;
    int i2 = node0 + nl2;
    if (i2 < N) hout[(size_t)i2 * 16 + j] = f2bf(o);
}

// ===========================================================================
// Head: bf16 h inputs (unchanged from round 10).
// ===========================================================================
__global__ __launch_bounds__(256)
void final_kernel(const unsigned short* __restrict__ h1,
                  const unsigned short* __restrict__ h2,
                  const unsigned short* __restrict__ h3,
                  const float* __restrict__ lw1, const float* __restrict__ lb1,
                  const float* __restrict__ lw2, const float* __restrict__ lb2,
                  float* __restrict__ out, int N) {
    constexpr int NPB = 64;
    __shared__ float s_lw1[48 * 64];
    __shared__ float s_lw2[64 * 4];
    __shared__ float s_lb1[64];
    __shared__ float s_lb2[4];
    __shared__ float s_c[NPB][49];

    int t = threadIdx.x;
    for (int idx = t; idx < 48 * 64; idx += 256) s_lw1[idx] = lw1[idx];
    s_lw2[t] = lw2[t];
    if (t < 64) s_lb1[t] = lb1[t];
    if (t < 4) s_lb2[t] = lb2[t];

    int nl = t >> 2;
    int l  = t & 3;
    int i  = blockIdx.x * NPB + nl;

    if (i < N) {
        ushort4 c1 = *(const ushort4*)(h1 + (size_t)i * 16 + l * 4);
        ushort4 c2 = *(const ushort4*)(h2 + (size_t)i * 16 + l * 4);
        ushort4 c3 = *(const ushort4*)(h3 + (size_t)i * 16 + l * 4);
        s_c[nl][l * 4 + 0] = bfu(c1.x); s_c[nl][l * 4 + 1] = bfu(c1.y);
        s_c[nl][l * 4 + 2] = bfu(c1.z); s_c[nl][l * 4 + 3] = bfu(c1.w);
        s_c[nl][16 + l * 4 + 0] = bfu(c2.x); s_c[nl][16 + l * 4 + 1] = bfu(c2.y);
        s_c[nl][16 + l * 4 + 2] = bfu(c2.z); s_c[nl][16 + l * 4 + 3] = bfu(c2.w);
        s_c[nl][32 + l * 4 + 0] = bfu(c3.x); s_c[nl][32 + l * 4 + 1] = bfu(c3.y);
        s_c[nl][32 + l * 4 + 2] = bfu(c3.z); s_c[nl][32 + l * 4 + 3] = bfu(c3.w);
    }
    __syncthreads();

    float o0 = 0.f, o1 = 0.f, o2 = 0.f, o3 = 0.f;
    if (i < N) {
#pragma unroll 4
        for (int jj = 0; jj < 16; ++jj) {
            int j = l * 16 + jj;
            float a = s_lb1[j];
#pragma unroll
            for (int k = 0; k < 48; ++k) a = fmaf(s_c[nl][k], s_lw1[k * 64 + j], a);
            a = a > 0.f ? a : 0.f;
            o0 = fmaf(a, s_lw2[j * 4 + 0], o0);
            o1 = fmaf(a, s_lw2[j * 4 + 1], o1);
            o2 = fmaf(a, s_lw2[j * 4 + 2], o2);
            o3 = fmaf(a, s_lw2[j * 4 + 3], o3);
        }
    }
    o0 += __shfl_xor(o0, 1); o0 += __shfl_xor(o0, 2);
    o1 += __shfl_xor(o1, 1); o1 += __shfl_xor(o1, 2);
    o2 += __shfl_xor(o2, 1); o2 += __shfl_xor(o2, 2);
    o3 += __shfl_xor(o3, 1); o3 += __shfl_xor(o3, 2);
    if (i < N && l == 0) {
        float4 o = {o0 + s_lb2[0], o1 + s_lb2[1], o2 + s_lb2[2], o3 + s_lb2[3]};
        *(float4*)(out + (size_t)i * 4) = o;
    }
}

// ===========================================================================
// Launch
// ===========================================================================
extern "C" void kernel_launch(void* const* d_in, const int* in_sizes, int n_in,
                              void* d_out, int out_size, void* d_ws, size_t ws_size,
                              hipStream_t stream) {
    const float* x  = (const float*)d_in[0];
    const int*   ei = (const int*)d_in[1];
    const float* ea = (const float*)d_in[2];
    const int N = in_sizes[0] / 32;
    const int E = in_sizes[1] / 2;
    const int* srci = ei;
    const int* dsti = ei + E;

    const float* lw1 = (const float*)d_in[33];
    const float* lb1 = (const float*)d_in[34];
    const float* lw2 = (const float*)d_in[35];
    const float* lb2 = (const float*)d_in[36];

    const int nbins = (N + BINW - 1) >> BINSHIFT;   // 1563
    const int chunk = (E + NBLK - 1) / NBLK;        // 1563

    // Workspace. tmp_meta/tmp_ea (32 MB) alias h1..h3 (bf16, 9.6 MB):
    // tmp dead after pass2, h first written by gine layer 1.
    char* p = (char*)d_ws;
    int*   binstart   = (int*)p;   p += (size_t)(nbins + 1 + 3) / 4 * 16;
    int*   bincnt     = (int*)p;   p += (size_t)(nbins + 3) / 4 * 16;
    int*   segsum     = (int*)p;   p += (size_t)(NSEG * nbins + 3) / 4 * 16;
    int*   rowstart   = (int*)p;   p += (size_t)(N + 1 + 3) / 4 * 16;
    unsigned* xbf     = (unsigned*)p; p += (size_t)N * 32 * 2;   // bf16 x
    int*   histmatT   = (int*)p;   p += (size_t)NBLK * nbins * 4;
    int*   basemat    = (int*)p;   p += (size_t)NBLK * nbins * 4;
    int*   src_sorted = (int*)p;   p += (size_t)E * 4;
    uint4* ea_sorted  = (uint4*)p; p += (size_t)E * 16;
    char*  u          = p;
    int*   tmp_meta   = (int*)u;                        // E*4
    uint4* tmp_ea     = (uint4*)(u + (size_t)E * 4);    // E*16
    unsigned short* h1 = (unsigned short*)u;            // N*16*2 each
    unsigned short* h2 = h1 + (size_t)N * 16;
    unsigned short* h3 = h2 + (size_t)N * 16;

    // ---- x -> bf16 (once) ----
    const int nword = N * 32 / 2;
    cvt_x_kernel<<<(nword + 255) / 256, 256, 0, stream>>>(x, xbf, nword);

    // ---- Counting sort (transposed-scan) + fine sort ----
    hist2d_kernel<<<NBLK, 256, 0, stream>>>(dsti, histmatT, E, nbins, chunk);
    colsum_kernel<<<(nbins + 255) / 256, 256, 0, stream>>>(histmatT, bincnt,
                                                           segsum, nbins);
    bin_scan_kernel<<<1, 1024, 0, stream>>>(bincnt, binstart, nbins, E);
    rowscan_kernel<<<dim3((nbins + 255) / 256, NSEG), 256, 0, stream>>>(
        histmatT, binstart, segsum, basemat, nbins);
    place_kernel<<<NBLK, 256, 0, stream>>>(srci, dsti, ea, basemat,
                                           tmp_meta, tmp_ea, E, nbins, chunk);
    pass2_kernel<<<nbins, 256, 0, stream>>>(binstart, tmp_meta, tmp_ea,
                                            rowstart, src_sorted, ea_sorted,
                                            N, E);

    // ---- Layers (wave-per-node, pair-unrolled, all-bf16 gathers) ----
    const int lblocks = (N + 15) / 16;
    gine_layer_wave<32, 8, 8><<<lblocks, 256, 0, stream>>>(
        (const unsigned short*)xbf, rowstart, src_sorted, ea_sorted,
        (const float*)d_in[3], (const float*)d_in[4],
        (const float*)d_in[5], (const float*)d_in[6],
        (const float*)d_in[7], (const float*)d_in[8],
        (const float*)d_in[9], (const float*)d_in[10],
        (const float*)d_in[11], (const float*)d_in[12], h1, N);

    gine_layer_wave<16, 4, 16><<<lblocks, 256, 0, stream>>>(
        h1, rowstart, src_sorted, ea_sorted,
        (const float*)d_in[13], (const float*)d_in[14],
        (const float*)d_in[15], (const float*)d_in[16],
        (const float*)d_in[17], (const float*)d_in[18],
        (const float*)d_in[19], (const float*)d_in[20],
        (const float*)d_in[21], (const float*)d_in[22], h2, N);

    gine_layer_wave<16, 4, 16><<<lblocks, 256, 0, stream>>>(
        h2, rowstart, src_sorted, ea_sorted,
        (const float*)d_in[23], (const float*)d_in[24],
        (const float*)d_in[25], (const float*)d_in[26],
        (const float*)d_in[27], (const float*)d_in[28],
        (const float*)d_in[29], (const float*)d_in[30],
        (const float*)d_in[31], (const float*)d_in[32], h3, N);

    // ---- Head ----
    final_kernel<<<(N + 63) / 64, 256, 0, stream>>>(
        h1, h2, h3, lw1, lb1, lw2, lb2, (float*)d_out, N);
}